// Round 1
// baseline (71.882 us; speedup 1.0000x reference)
//
#include <hip/hip_runtime.h>

// Problem: inclusive prefix-sum along L of X[B=8][L=4096][D=64][N=16] fp32.
// dn = d*16+n is contiguous (1024 floats per (b,l)); scan stride = 4096 B.

constexpr int BB = 8;
constexpr int LL = 4096;
constexpr int DN = 1024;      // D*N
constexpr int C  = 64;        // chunks per column
constexpr int S  = LL / C;    // 64 rows per chunk
constexpr int TPB = 256;      // threads per block; each thread owns 4 dn (float4)

// Pass 1: per-chunk column sums. grid = B*C blocks, 256 thr. csum[(b*C+c)*DN + dn]
__global__ __launch_bounds__(TPB) void scan_pass1(const float* __restrict__ x,
                                                  float* __restrict__ csum) {
    const int bid = blockIdx.x;         // b*C + c
    const int b = bid / C, c = bid % C;
    const int dn4 = threadIdx.x;        // float4 column group
    const float4* xp = reinterpret_cast<const float4*>(
        x + (size_t)b * LL * DN + (size_t)c * S * DN) + dn4;
    float4 acc = make_float4(0.f, 0.f, 0.f, 0.f);
    #pragma unroll 8
    for (int i = 0; i < S; ++i) {
        float4 v = xp[(size_t)i * (DN / 4)];
        acc.x += v.x; acc.y += v.y; acc.z += v.z; acc.w += v.w;
    }
    reinterpret_cast<float4*>(csum + (size_t)bid * DN)[dn4] = acc;
}

// Pass 2: exclusive scan of the C chunk sums per (b, dn). B*DN/4 = 2048 threads.
__global__ __launch_bounds__(TPB) void scan_pass2(float* __restrict__ csum) {
    const int gid = blockIdx.x * TPB + threadIdx.x;   // 0 .. B*256-1
    const int b = gid / (DN / 4), dn4 = gid % (DN / 4);
    float4 run = make_float4(0.f, 0.f, 0.f, 0.f);
    for (int c = 0; c < C; ++c) {
        float4* p = reinterpret_cast<float4*>(csum + (size_t)(b * C + c) * DN) + dn4;
        float4 v = *p;
        *p = run;
        run.x += v.x; run.y += v.y; run.z += v.z; run.w += v.w;
    }
}

// Pass 3: running scan per chunk starting from exclusive offset; write out.
__global__ __launch_bounds__(TPB) void scan_pass3(const float* __restrict__ x,
                                                  const float* __restrict__ csum,
                                                  float* __restrict__ out) {
    const int bid = blockIdx.x;
    const int b = bid / C, c = bid % C;
    const int dn4 = threadIdx.x;
    const size_t base = (size_t)b * LL * DN + (size_t)c * S * DN;
    const float4* xp = reinterpret_cast<const float4*>(x + base) + dn4;
    float4* op = reinterpret_cast<float4*>(out + base) + dn4;
    float4 run = reinterpret_cast<const float4*>(csum + (size_t)bid * DN)[dn4];
    #pragma unroll 4
    for (int i = 0; i < S; ++i) {
        float4 v = xp[(size_t)i * (DN / 4)];
        run.x += v.x; run.y += v.y; run.z += v.z; run.w += v.w;
        op[(size_t)i * (DN / 4)] = run;
    }
}

extern "C" void kernel_launch(void* const* d_in, const int* in_sizes, int n_in,
                              void* d_out, int out_size, void* d_ws, size_t ws_size,
                              hipStream_t stream) {
    const float* x = (const float*)d_in[0];
    float* out = (float*)d_out;
    float* csum = (float*)d_ws;   // needs B*C*DN*4 = 2 MiB

    dim3 grid1(BB * C), blk(TPB);
    scan_pass1<<<grid1, blk, 0, stream>>>(x, csum);
    scan_pass2<<<dim3((BB * DN / 4) / TPB), blk, 0, stream>>>(csum);
    scan_pass3<<<grid1, blk, 0, stream>>>(x, csum, out);
}